// Round 11
// baseline (926.389 us; speedup 1.0000x reference)
//
#include <hip/hip_runtime.h>
#include <stdint.h>

// GeneralConv fused pipeline for MI355X (gfx950) — v11.
// Bond layer1 factorized: x@W0 = PS[src] + QS[dst] + edge_feat@W0e (CSR order).
// v11: bond + node run as 1024-thread blocks (16 waves share one 141-150KB LDS
// weight image -> 4 waves/SIMD instead of 2; v10 proved the tile body fits in
// 124 VGPR, so the 128-reg cap at 4 waves/EU is satisfiable). node restructured
// to 16-node tiles (bond-style) so its accumulators fit the 128-reg cap.
// pq/zn keep 512thr/2-wave (their acc[2][16]=128xf32x4 cannot fit 128 regs).

#define NN 50000
#define NE 800000
#define NPART 196        // ceil(NN/256)
#define NTILE_N 1563     // ceil(NN/32)  (pq/zn 32-row tiles)
#define NTILE_N16 3125   // ceil(NN/16)  (node 16-row tiles)
#define NTILE_E16 50000  // NE/16

typedef short bf16x8 __attribute__((ext_vector_type(8)));
typedef float f32x4 __attribute__((ext_vector_type(4)));

#define MFMA16(a, b, c) __builtin_amdgcn_mfma_f32_16x16x32_bf16((a), (b), (c), 0, 0, 0)

union U8 { uint4 q; bf16x8 v; };

__device__ __forceinline__ uint32_t f2bf(float f) {
  union { float f; uint32_t u; } x; x.f = f;
  uint32_t u = x.u;
  u += 0x7FFFu + ((u >> 16) & 1u);   // RNE
  return u >> 16;
}
__device__ __forceinline__ float bf2f(uint32_t lo16) {
  union { uint32_t u; float f; } x; x.u = lo16 << 16; return x.f;
}
__device__ __forceinline__ float sigm(float x) { return 1.0f / (1.0f + __expf(-x)); }
__device__ __forceinline__ float silu(float x) { return x * sigm(x); }
__device__ __forceinline__ uint32_t packbf2(float a, float b) {
  return f2bf(a) | (f2bf(b) << 16);
}
__device__ __forceinline__ bf16x8 pack8(float4 a, float4 b) {
  U8 u;
  u.q.x = packbf2(a.x, a.y); u.q.y = packbf2(a.z, a.w);
  u.q.z = packbf2(b.x, b.y); u.q.w = packbf2(b.z, b.w);
  return u.v;
}
__device__ __forceinline__ f32x4 cvt4u(uint32_t a, uint32_t b) {
  f32x4 r;
  r[0] = bf2f(a & 0xffffu); r[1] = bf2f(a >> 16);
  r[2] = bf2f(b & 0xffffu); r[3] = bf2f(b >> 16);
  return r;
}
__device__ __forceinline__ f32x4 add4(f32x4 a, f32x4 b) {
  f32x4 r; r[0] = a[0] + b[0]; r[1] = a[1] + b[1]; r[2] = a[2] + b[2]; r[3] = a[3] + b[3];
  return r;
}
// swizzled LDS weight-fragment read: region layout [rows][128 k] bf16, 256B rows
__device__ __forceinline__ bf16x8 ldw(const char* base, int row, int kc, int lg) {
  return *(const bf16x8*)(base + ((row * 256 + kc * 64 + lg * 16) ^ ((row & 7) << 4)));
}
__device__ __forceinline__ void stage_w(char* dst, const unsigned short* src,
                                        int tid, int nthr) {
  for (int g = tid; g < 4096; g += nthr) {
    int row = g >> 4, slot = g & 15;
    *(uint4*)(dst + ((row * 256 + slot * 16) ^ ((row & 7) << 4))) =
        *(const uint4*)(src + row * 128 + slot * 8);
  }
}

// ---------------------------------------------------------------------------
// combined weight pack: 12 transpose jobs + zn pack, one launch
// ---------------------------------------------------------------------------
__global__ __launch_bounds__(256) void packmulti(
    const float* __restrict__ bWm0, const float* __restrict__ bWg0,
    const float* __restrict__ bWm1, const float* __restrict__ bWg1,
    const float* __restrict__ nWm0, const float* __restrict__ nWg0,
    const float* __restrict__ nWm1, const float* __restrict__ nWg1,
    unsigned short* __restrict__ bondW0eT, unsigned short* __restrict__ bondW1T,
    unsigned short* __restrict__ pqPW, unsigned short* __restrict__ pqQW,
    unsigned short* __restrict__ nodeWaggT, unsigned short* __restrict__ nodeW1T,
    unsigned short* __restrict__ znW) {
  int b = blockIdx.x;
  if (b < 768) {
    int job = b >> 6;
    const float* W; int rb; unsigned short* WT; int c0;
    switch (job) {
      case 0:  W = bWm0; rb = 256; WT = bondW0eT;  c0 = 0;   break;
      case 1:  W = bWg0; rb = 256; WT = bondW0eT;  c0 = 128; break;
      case 2:  W = bWm1; rb = 0;   WT = bondW1T;   c0 = 0;   break;
      case 3:  W = bWg1; rb = 0;   WT = bondW1T;   c0 = 128; break;
      case 4:  W = bWm0; rb = 0;   WT = pqPW;      c0 = 0;   break;
      case 5:  W = bWg0; rb = 0;   WT = pqPW;      c0 = 128; break;
      case 6:  W = bWm0; rb = 128; WT = pqQW;      c0 = 0;   break;
      case 7:  W = bWg0; rb = 128; WT = pqQW;      c0 = 128; break;
      case 8:  W = nWm0; rb = 128; WT = nodeWaggT; c0 = 0;   break;
      case 9:  W = nWg0; rb = 128; WT = nodeWaggT; c0 = 128; break;
      case 10: W = nWm1; rb = 0;   WT = nodeW1T;   c0 = 0;   break;
      default: W = nWg1; rb = 0;   WT = nodeW1T;   c0 = 128; break;
    }
    int id = (b & 63) * 256 + threadIdx.x;
    int c = id >> 7, k = id & 127;
    WT[(size_t)(c0 + c) * 128 + k] = (unsigned short)f2bf(W[(size_t)(rb + k) * 128 + c]);
  } else {
    // znW [256 c][288 k]: k<128 node_inp rows, 128..255 coords rows(+256), 256 = gs row 384
    int id = (b - 768) * 256 + threadIdx.x;
    if (id >= 256 * 288) return;
    int c = id / 288, k = id - c * 288;
    const float* W = (c < 128) ? nWm0 : nWg0;
    int cc = c & 127;
    float v = 0.0f;
    if (k < 128) v = W[(size_t)k * 128 + cc];
    else if (k < 256) v = W[(size_t)(128 + k) * 128 + cc];   // row 256+(k-128)
    else if (k == 256) v = W[(size_t)384 * 128 + cc];
    znW[id] = (unsigned short)f2bf(v);
  }
}

// ---------------- CSR build ----------------
__global__ __launch_bounds__(256) void hist_kernel(const int* __restrict__ ei,
                                                   int* __restrict__ cnt) {
  int e = blockIdx.x * 256 + threadIdx.x;
  if (e < NE) atomicAdd(&cnt[ei[e]], 1);
}

__global__ __launch_bounds__(256) void scan1(const int* __restrict__ cnt,
                                             int* __restrict__ partials) {
  int t = threadIdx.x;
  int i = blockIdx.x * 256 + t;
  int v = (i < NN) ? cnt[i] : 0;
#pragma unroll
  for (int d = 1; d < 64; d <<= 1) v += __shfl_xor(v, d, 64);
  __shared__ int ws4[4];
  if ((t & 63) == 0) ws4[t >> 6] = v;
  __syncthreads();
  if (t == 0) partials[blockIdx.x] = ws4[0] + ws4[1] + ws4[2] + ws4[3];
}

__global__ __launch_bounds__(256) void scan2(int* __restrict__ partials,
                                             int* __restrict__ offsets) {
  int t = threadIdx.x;
  int v = (t < NPART) ? partials[t] : 0;
  int incl = v;
#pragma unroll
  for (int d = 1; d < 64; d <<= 1) {
    int u = __shfl_up(incl, d, 64);
    if ((t & 63) >= d) incl += u;
  }
  __shared__ int wsum[4];
  if ((t & 63) == 63) wsum[t >> 6] = incl;
  __syncthreads();
  int add = 0;
  for (int w = 0; w < (t >> 6); ++w) add += wsum[w];
  incl += add;
  if (t < NPART) partials[t] = incl - v;
  if (t == 255) offsets[NN] = incl;
}

__global__ __launch_bounds__(256) void scan3(const int* __restrict__ cnt,
                                             const int* __restrict__ partials,
                                             int* __restrict__ offsets,
                                             int* __restrict__ cursor) {
  int t = threadIdx.x;
  int i = blockIdx.x * 256 + t;
  int v = (i < NN) ? cnt[i] : 0;
  int incl = v;
#pragma unroll
  for (int d = 1; d < 64; d <<= 1) {
    int u = __shfl_up(incl, d, 64);
    if ((t & 63) >= d) incl += u;
  }
  __shared__ int wsum[4];
  if ((t & 63) == 63) wsum[t >> 6] = incl;
  __syncthreads();
  int add = partials[blockIdx.x];
  for (int w = 0; w < (t >> 6); ++w) add += wsum[w];
  int excl = incl - v + add;
  if (i < NN) { offsets[i] = excl; cursor[i] = excl; }
}

__global__ __launch_bounds__(256) void fill_kernel(const int* __restrict__ ei,
                                                   int* __restrict__ cursor,
                                                   int* __restrict__ eidS,
                                                   int* __restrict__ srcS,
                                                   int* __restrict__ dstS) {
  int e = blockIdx.x * 256 + threadIdx.x;
  if (e >= NE) return;
  int s = ei[e], d = ei[NE + e];
  int pos = atomicAdd(&cursor[s], 1);
  eidS[pos] = e; srcS[pos] = s; dstS[pos] = d;
}

// ---------------------------------------------------------------------------
// pq_kernel: INTERLEAVED tables.
// PSI[n][hf][lg][m4|g4]: m = (ni@Wm0[0:128]+bm0)[hf*16+lg*4..+3], g analog.
// QSI same from Wm0[128:256]/Wg0[128:256], no bias.
// ---------------------------------------------------------------------------
template <bool BIAS>
__device__ __forceinline__ void pq_table(const char* wbase, const bf16x8 (&xf)[2][4],
                                         const float* bm, const float* bg,
                                         unsigned short* out, int tb, int lg, int lr) {
  f32x4 acc[2][16] = {};
#pragma unroll
  for (int kc = 0; kc < 4; ++kc)
#pragma unroll
    for (int cf = 0; cf < 16; ++cf) {
      bf16x8 a = ldw(wbase, cf * 16 + lr, kc, lg);
      acc[0][cf] = MFMA16(a, xf[0][kc], acc[0][cf]);
      acc[1][cf] = MFMA16(a, xf[1][kc], acc[1][cf]);
    }
#pragma unroll
  for (int cf = 0; cf < 16; ++cf) {
    int c = cf * 16 + lg * 4;                 // channel within branch block
    float4 b = make_float4(0.f, 0.f, 0.f, 0.f);
    if (BIAS) b = *(const float4*)((cf < 8) ? (bm + c) : (bg + (c - 128)));
    int hf = cf & 7;
    int off = hf * 32 + lg * 8 + ((cf >= 8) ? 4 : 0);   // interleaved position
#pragma unroll
    for (int et = 0; et < 2; ++et) {
      int n = tb + et * 16 + lr;
      if (n < NN) {
        f32x4 v = acc[et][cf];
        uint2 pk = make_uint2(packbf2(v[0] + b.x, v[1] + b.y),
                              packbf2(v[2] + b.z, v[3] + b.w));
        *(uint2*)(out + (size_t)n * 256 + off) = pk;
      }
    }
  }
}

__global__ __launch_bounds__(512, 2) void pq_kernel(
    const float* __restrict__ ni,
    const unsigned short* __restrict__ pW, const unsigned short* __restrict__ qW,
    const float* __restrict__ bbm0, const float* __restrict__ bbg0,
    unsigned short* __restrict__ PSI, unsigned short* __restrict__ QSI) {
  __shared__ char sm[131072];
  const int t = threadIdx.x, lane = t & 63, wv = t >> 6, lg = lane >> 4, lr = lane & 15;
  stage_w(sm, pW, t, 512);
  stage_w(sm + 65536, qW, t, 512);
  __syncthreads();
  int tile = blockIdx.x * 8 + wv;
  if (tile >= NTILE_N) return;
  int tb = tile * 32;
  int n0 = min(tb + lr, NN - 1), n1 = min(tb + 16 + lr, NN - 1);
  bf16x8 xf[2][4];
#pragma unroll
  for (int kc = 0; kc < 4; ++kc) {
    const float* p0 = ni + (size_t)n0 * 128 + kc * 32 + lg * 8;
    const float* p1 = ni + (size_t)n1 * 128 + kc * 32 + lg * 8;
    xf[0][kc] = pack8(((const float4*)p0)[0], ((const float4*)p0)[1]);
    xf[1][kc] = pack8(((const float4*)p1)[0], ((const float4*)p1)[1]);
  }
  pq_table<true>(sm, xf, bbm0, bbg0, PSI, tb, lg, lr);
  pq_table<false>(sm + 65536, xf, nullptr, nullptr, QSI, tb, lg, lr);
}

// ---------------------------------------------------------------------------
// zn_kernel: Znode[n][256] bf16 = [zm|zg] (plain layout), z = ni@W[0:128] +
// coords@W[256:384] + gs*W[384] + b0. Weights [256][288] = 144KB LDS.
// ---------------------------------------------------------------------------
__global__ __launch_bounds__(512, 2) void zn_kernel(
    const float* __restrict__ ni, const float* __restrict__ coords,
    const float* __restrict__ gs, const unsigned short* __restrict__ znW,
    const float* __restrict__ nbm0, const float* __restrict__ nbg0,
    unsigned short* __restrict__ ZN) {
  __shared__ char sm[147456];
  const int t = threadIdx.x, lane = t & 63, wv = t >> 6, lg = lane >> 4, lr = lane & 15;
  for (int g = t; g < 256 * 36; g += 512) {
    int row = g / 36, slot = g - row * 36;
    *(uint4*)(sm + ((row * 576 + slot * 16) ^ ((row & 7) << 4))) =
        *(const uint4*)(znW + row * 288 + slot * 8);
  }
  __syncthreads();
  int tile = blockIdx.x * 8 + wv;
  if (tile >= NTILE_N) return;
  int tb = tile * 32;
  int n0 = min(tb + lr, NN - 1), n1 = min(tb + 16 + lr, NN - 1);
  f32x4 acc[2][16] = {};
#pragma unroll
  for (int kc = 0; kc < 9; ++kc) {
    bf16x8 x0, x1;
    if (kc < 8) {
      const float* base = (kc < 4) ? ni : coords;
      int ko = (kc & 3) * 32 + lg * 8;
      const float* p0 = base + (size_t)n0 * 128 + ko;
      const float* p1 = base + (size_t)n1 * 128 + ko;
      x0 = pack8(((const float4*)p0)[0], ((const float4*)p0)[1]);
      x1 = pack8(((const float4*)p1)[0], ((const float4*)p1)[1]);
    } else {
      U8 z0, z1;
      z0.q = make_uint4(0, 0, 0, 0); z1.q = make_uint4(0, 0, 0, 0);
      if (lg == 0) { z0.q.x = f2bf(gs[n0]); z1.q.x = f2bf(gs[n1]); }
      x0 = z0.v; x1 = z1.v;
    }
#pragma unroll
    for (int cf = 0; cf < 16; ++cf) {
      int row = cf * 16 + lr;
      bf16x8 a = *(const bf16x8*)(sm + ((row * 576 + kc * 64 + lg * 16) ^ ((row & 7) << 4)));
      acc[0][cf] = MFMA16(a, x0, acc[0][cf]);
      acc[1][cf] = MFMA16(a, x1, acc[1][cf]);
    }
  }
#pragma unroll
  for (int cf = 0; cf < 16; ++cf) {
    int c = cf * 16 + lg * 4;
    float4 b = *(const float4*)((cf < 8) ? (nbm0 + c) : (nbg0 + (c - 128)));
#pragma unroll
    for (int et = 0; et < 2; ++et) {
      int n = tb + et * 16 + lr;
      if (n < NN) {
        f32x4 v = acc[et][cf];
        uint2 pk = make_uint2(packbf2(v[0] + b.x, v[1] + b.y),
                              packbf2(v[2] + b.z, v[3] + b.w));
        *(uint2*)(ZN + (size_t)n * 256 + c) = pk;
      }
    }
  }
}

// 16-row layer2 (bond + node): silu(acc) -> per-wave LDS scratch [16][72B]
// -> B-frags -> MFMA with LDS-staged W1 rows [rowoff..rowoff+128).
__device__ __forceinline__ void layer2_16(const f32x4 (&acc)[8], f32x4 (&acc2)[8],
                                          const char* w1, int rowoff, char* scr,
                                          int lg, int lr) {
#pragma unroll
  for (int q = 0; q < 4; ++q) {
#pragma unroll
    for (int hq = 0; hq < 2; ++hq) {
      f32x4 z = acc[q * 2 + hq];
      uint2 pk = make_uint2(packbf2(silu(z[0]), silu(z[1])),
                            packbf2(silu(z[2]), silu(z[3])));
      *(uint2*)(scr + lr * 72 + hq * 32 + lg * 8) = pk;
    }
    bf16x8 h = *(const bf16x8*)(scr + lr * 72 + lg * 16);
#pragma unroll
    for (int hf2 = 0; hf2 < 8; ++hf2) {
      bf16x8 a = ldw(w1, rowoff + hf2 * 16 + lr, q, lg);
      acc2[hf2] = MFMA16(a, h, acc2[hf2]);
    }
  }
}

// ---------------------------------------------------------------------------
// bond_v11: 1024 threads = 16 waves sharing one LDS weight image -> 4 waves/
// SIMD. 16-edge tiles, CSR order, batch-staged gathers, barrier-free loop.
// ---------------------------------------------------------------------------
__global__ __launch_bounds__(1024, 4) void bond_v11(
    const float* __restrict__ ef,
    const int* __restrict__ srcS, const int* __restrict__ dstS,
    const int* __restrict__ eidS,
    const unsigned short* __restrict__ W0eT, const unsigned short* __restrict__ W1T,
    const unsigned short* __restrict__ PSI, const unsigned short* __restrict__ QSI,
    const float* __restrict__ bbm1, const float* __restrict__ bbg1,
    unsigned short* __restrict__ concat) {
  __shared__ char sm[150528];   // W0e 64K | W1 64K | biases 1K | scratch 16*1152
  const int t = threadIdx.x, lane = t & 63, wv = t >> 6, lg = lane >> 4, lr = lane & 15;
  stage_w(sm, W0eT, t, 1024);          // rows 0..127 m, 128..255 g (K=128)
  stage_w(sm + 65536, W1T, t, 1024);   // rows 0..127 W1m, 128..255 W1g
  if (t < 128) {
    ((float*)(sm + 131072))[t] = bbm1[t];
    ((float*)(sm + 131584))[t] = bbg1[t];
  }
  __syncthreads();
  char* scr = sm + 132096 + wv * 1152;

  const int wid = blockIdx.x * 16 + wv;   // 4096 waves
  // balanced split: 50000 = 4096*12 + 848 -> first 848 waves take 13 tiles
  const int extra = min(wid, 848);
  const int start = wid * 12 + extra;
  const int end = min(start + 12 + (wid < 848 ? 1 : 0), NTILE_E16);
  if (start >= end) return;

  // preload first tile's indices (per-lane: edge tb+lr)
  int s0 = srcS[start * 16 + lr];
  int d0 = dstS[start * 16 + lr];
  int ed0 = eidS[start * 16 + lr];

  for (int tile = start; tile < end; ++tile) {
    const int tb = tile * 16;
    // ---- issue ALL gathers for this tile as one batch ----
    uint4 P[8], Q[8];
    const unsigned short* pp = PSI + (size_t)s0 * 256 + lg * 8;
    const unsigned short* qq = QSI + (size_t)d0 * 256 + lg * 8;
#pragma unroll
    for (int hf = 0; hf < 8; ++hf) {
      P[hf] = *(const uint4*)(pp + hf * 32);
      Q[hf] = *(const uint4*)(qq + hf * 32);
    }
    float4 E[8];
    const float* eb = ef + (size_t)ed0 * 128 + lg * 8;
#pragma unroll
    for (int kq = 0; kq < 8; ++kq)
      E[kq] = ((const float4*)(eb + (kq >> 1) * 32))[kq & 1];
    // ---- prefetch next tile's indices (independent of this tile) ----
    if (tile + 1 < end) {
      int en = (tile + 1) * 16 + lr;
      s0 = srcS[en]; d0 = dstS[en]; ed0 = eidS[en];
    }

    // ---- acc init from P+Q (interleaved m4|g4) ----
    f32x4 accm[8], accg[8];
#pragma unroll
    for (int hf = 0; hf < 8; ++hf) {
      accm[hf] = add4(cvt4u(P[hf].x, P[hf].y), cvt4u(Q[hf].x, Q[hf].y));
      accg[hf] = add4(cvt4u(P[hf].z, P[hf].w), cvt4u(Q[hf].z, Q[hf].w));
    }

    // ---- layer1: + edge_feat @ W0e ----
#pragma unroll
    for (int kc = 0; kc < 4; ++kc) {
      bf16x8 x = pack8(E[kc * 2], E[kc * 2 + 1]);
#pragma unroll
      for (int hf = 0; hf < 8; ++hf) {
        accm[hf] = MFMA16(ldw(sm, hf * 16 + lr, kc, lg), x, accm[hf]);
        accg[hf] = MFMA16(ldw(sm, 128 + hf * 16 + lr, kc, lg), x, accg[hf]);
      }
    }

    // ---- layer2 both branches ----
    f32x4 acc2m[8] = {};
    layer2_16(accm, acc2m, sm + 65536, 0, scr, lg, lr);
    f32x4 acc2g[8] = {};
    layer2_16(accg, acc2g, sm + 65536, 128, scr, lg, lr);

    // ---- combine m * sigmoid(g); contiguous store at CSR slot ----
#pragma unroll
    for (int hf2 = 0; hf2 < 8; ++hf2) {
      float4 b1m = *(const float4*)(sm + 131072 + (hf2 * 16 + lg * 4) * 4);
      float4 b1g = *(const float4*)(sm + 131584 + (hf2 * 16 + lg * 4) * 4);
      f32x4 m = acc2m[hf2], g = acc2g[hf2];
      uint2 pk = make_uint2(
          packbf2((m[0] + b1m.x) * sigm(g[0] + b1g.x),
                  (m[1] + b1m.y) * sigm(g[1] + b1g.y)),
          packbf2((m[2] + b1m.z) * sigm(g[2] + b1g.z),
                  (m[3] + b1m.w) * sigm(g[3] + b1g.w)));
      *(uint2*)(concat + (size_t)(tb + lr) * 128 + hf2 * 16 + lg * 4) = pk;
    }
  }
}

// segment mean over CSR-contiguous concat rows -> agg[N][128] bf16 (streaming)
__global__ __launch_bounds__(256) void agg_kernel(const int* __restrict__ offsets,
                                                  const unsigned short* __restrict__ concat,
                                                  unsigned short* __restrict__ agg) {
  int n = blockIdx.x * 4 + (threadIdx.x >> 6);
  if (n >= NN) return;
  int lane = threadIdx.x & 63;
  int s0 = offsets[n], s1 = offsets[n + 1];
  float a0 = 0.f, a1 = 0.f;
  const uint32_t* p = (const uint32_t*)concat + lane;
  for (int s = s0; s < s1; ++s) {
    uint32_t v = p[(size_t)s * 64];
    a0 += bf2f(v & 0xffffu);
    a1 += bf2f(v >> 16);
  }
  float inv = (s1 > s0) ? 1.f / (float)(s1 - s0) : 0.f;
  ((uint32_t*)agg)[(size_t)n * 64 + lane] = packbf2(a0 * inv, a1 * inv);
}

// ---------------------------------------------------------------------------
// node_v11: 1024 threads = 16 waves, 16-node tiles (bond-style; fits 128-reg
// cap). acc init from Znode, + agg@Wagg (K=128), layer2, fused LayerNorm.
// ---------------------------------------------------------------------------
__global__ __launch_bounds__(1024, 4) void node_v11(
    const unsigned short* __restrict__ agg, const unsigned short* __restrict__ ZN,
    const unsigned short* __restrict__ WaggT, const unsigned short* __restrict__ W1T,
    const float* __restrict__ nbm1, const float* __restrict__ nbg1,
    const float* __restrict__ gamma, const float* __restrict__ beta,
    float* __restrict__ out) {
  __shared__ char sm[151552];   // Wagg 64K | W1 64K | consts 2K | scratch 16*1152
  const int t = threadIdx.x, lane = t & 63, wv = t >> 6, lg = lane >> 4, lr = lane & 15;
  stage_w(sm, WaggT, t, 1024);
  stage_w(sm + 65536, W1T, t, 1024);
  if (t < 128) {
    ((float*)(sm + 131072))[t] = nbm1[t];
    ((float*)(sm + 131584))[t] = nbg1[t];
    ((float*)(sm + 132096))[t] = gamma[t];
    ((float*)(sm + 132608))[t] = beta[t];
  }
  __syncthreads();
  char* scr = sm + 133120 + wv * 1152;

  int tile = blockIdx.x * 16 + wv;
  if (tile >= NTILE_N16) return;
  int tb = tile * 16;
  int n0 = min(tb + lr, NN - 1);

  // acc init from Znode (plain [n][zm128|zg128])
  f32x4 accm[8], accg[8];
  {
    uint2 zm[8], zg[8];
#pragma unroll
    for (int hf = 0; hf < 8; ++hf) {
      const unsigned short* p0 = ZN + (size_t)n0 * 256 + hf * 16 + lg * 4;
      zm[hf] = *(const uint2*)p0;
      zg[hf] = *(const uint2*)(p0 + 128);
    }
#pragma unroll
    for (int hf = 0; hf < 8; ++hf) {
      accm[hf] = cvt4u(zm[hf].x, zm[hf].y);
      accg[hf] = cvt4u(zg[hf].x, zg[hf].y);
    }
  }
  // + agg @ Wagg
#pragma unroll
  for (int kc = 0; kc < 4; ++kc) {
    bf16x8 x = *(const bf16x8*)(agg + (size_t)n0 * 128 + kc * 32 + lg * 8);
#pragma unroll
    for (int hf = 0; hf < 8; ++hf) {
      accm[hf] = MFMA16(ldw(sm, hf * 16 + lr, kc, lg), x, accm[hf]);
      accg[hf] = MFMA16(ldw(sm, 128 + hf * 16 + lr, kc, lg), x, accg[hf]);
    }
  }

  f32x4 acc2m[8] = {};
  layer2_16(accm, acc2m, sm + 65536, 0, scr, lg, lr);
  f32x4 acc2g[8] = {};
  layer2_16(accg, acc2g, sm + 65536, 128, scr, lg, lr);

  // combine + LayerNorm + f32 store
  float v[8][4];
  float s = 0.f, ss = 0.f;
#pragma unroll
  for (int hf2 = 0; hf2 < 8; ++hf2) {
    float4 b1m = *(const float4*)(sm + 131072 + (hf2 * 16 + lg * 4) * 4);
    float4 b1g = *(const float4*)(sm + 131584 + (hf2 * 16 + lg * 4) * 4);
    f32x4 m = acc2m[hf2], g = acc2g[hf2];
    v[hf2][0] = (m[0] + b1m.x) * sigm(g[0] + b1g.x);
    v[hf2][1] = (m[1] + b1m.y) * sigm(g[1] + b1g.y);
    v[hf2][2] = (m[2] + b1m.z) * sigm(g[2] + b1g.z);
    v[hf2][3] = (m[3] + b1m.w) * sigm(g[3] + b1g.w);
#pragma unroll
    for (int r = 0; r < 4; ++r) { s += v[hf2][r]; ss += v[hf2][r] * v[hf2][r]; }
  }
  s += __shfl_xor(s, 16, 64);  ss += __shfl_xor(ss, 16, 64);
  s += __shfl_xor(s, 32, 64);  ss += __shfl_xor(ss, 32, 64);
  float mu = s * 0.0078125f;
  float var = ss * 0.0078125f - mu * mu;
  float rs = rsqrtf(var + 1e-5f);
  int n = tb + lr;
  if (n < NN) {
#pragma unroll
    for (int hf2 = 0; hf2 < 8; ++hf2) {
      float4 gm = *(const float4*)(sm + 132096 + (hf2 * 16 + lg * 4) * 4);
      float4 bt = *(const float4*)(sm + 132608 + (hf2 * 16 + lg * 4) * 4);
      float4 o;
      o.x = (v[hf2][0] - mu) * rs * gm.x + bt.x;
      o.y = (v[hf2][1] - mu) * rs * gm.y + bt.y;
      o.z = (v[hf2][2] - mu) * rs * gm.z + bt.z;
      o.w = (v[hf2][3] - mu) * rs * gm.w + bt.w;
      *(float4*)(out + (size_t)n * 128 + hf2 * 16 + lg * 4) = o;
    }
  }
}

extern "C" void kernel_launch(void* const* d_in, const int* in_sizes, int n_in,
                              void* d_out, int out_size, void* d_ws, size_t ws_size,
                              hipStream_t stream) {
  const float* node_inp = (const float*)d_in[0];
  const float* edge_feat = (const float*)d_in[1];
  const float* gstate = (const float*)d_in[2];
  const float* coords = (const float*)d_in[4];
  const int* edge_index = (const int*)d_in[5];
  const float* bWm0 = (const float*)d_in[6];  const float* bbm0 = (const float*)d_in[7];
  const float* bWm1 = (const float*)d_in[8];  const float* bbm1 = (const float*)d_in[9];
  const float* bWg0 = (const float*)d_in[10]; const float* bbg0 = (const float*)d_in[11];
  const float* bWg1 = (const float*)d_in[12]; const float* bbg1 = (const float*)d_in[13];
  const float* nWm0 = (const float*)d_in[14]; const float* nbm0 = (const float*)d_in[15];
  const float* nWm1 = (const float*)d_in[16]; const float* nbm1 = (const float*)d_in[17];
  const float* nWg0 = (const float*)d_in[18]; const float* nbg0 = (const float*)d_in[19];
  const float* nWg1 = (const float*)d_in[20]; const float* nbg1 = (const float*)d_in[21];
  const float* gamma = (const float*)d_in[22]; const float* beta = (const float*)d_in[23];

  char* ws = (char*)d_ws;
  size_t o = 0;
  auto alloc = [&](size_t bytes) {
    size_t r = o; o = (o + bytes + 255) & ~(size_t)255; return r;
  };
  unsigned short* QSI  = (unsigned short*)(ws + alloc((size_t)NN * 256 * 2)); // 25.6MB
  int* offsets         = (int*)(ws + alloc((size_t)(NN + 1) * 4));
  int* eidS            = (int*)(ws + alloc((size_t)NE * 4));
  int* srcS            = (int*)(ws + alloc((size_t)NE * 4));
  int* dstS            = (int*)(ws + alloc((size_t)NE * 4));
  unsigned short* bondW0eT  = (unsigned short*)(ws + alloc(256 * 128 * 2));
  unsigned short* bondW1T   = (unsigned short*)(ws + alloc(256 * 128 * 2));
  unsigned short* pqPW      = (unsigned short*)(ws + alloc(256 * 128 * 2));
  unsigned short* pqQW      = (unsigned short*)(ws + alloc(256 * 128 * 2));
  unsigned short* znW       = (unsigned short*)(ws + alloc(256 * 288 * 2));
  unsigned short* nodeWaggT = (unsigned short*)(ws + alloc(256 * 128 * 2));
  unsigned short* nodeW1T   = (unsigned short*)(ws + alloc(256 * 128 * 2));
  char* concatR        = ws + alloc((size_t)NE * 128 * 2);                   // 204.8MB
  // overlays (lifetime-disjoint):
  unsigned short* PSI = (unsigned short*)d_out;          // dead before node_v11 writes
  unsigned short* agg = QSI;                             // QSI dead after bond
  int* cnt      = (int*)concatR;                         // pre-bond
  int* partials = (int*)(concatR + (1 << 20));           // pre-bond
  int* cursor   = (int*)(concatR + (2 << 20));           // pre-bond
  unsigned short* ZN = (unsigned short*)(concatR + (4 << 20));  // after agg
  unsigned short* concat = (unsigned short*)concatR;

  hipMemsetAsync(cnt, 0, (size_t)NN * 4, stream);

  packmulti<<<1056, 256, 0, stream>>>(bWm0, bWg0, bWm1, bWg1, nWm0, nWg0, nWm1, nWg1,
                                      bondW0eT, bondW1T, pqPW, pqQW,
                                      nodeWaggT, nodeW1T, znW);

  hist_kernel<<<NE / 256, 256, 0, stream>>>(edge_index, cnt);
  scan1<<<NPART, 256, 0, stream>>>(cnt, partials);
  scan2<<<1, 256, 0, stream>>>(partials, offsets);
  scan3<<<NPART, 256, 0, stream>>>(cnt, partials, offsets, cursor);
  fill_kernel<<<NE / 256, 256, 0, stream>>>(edge_index, cursor, eidS, srcS, dstS);

  pq_kernel<<<196, 512, 0, stream>>>(node_inp, pqPW, pqQW, bbm0, bbg0, PSI, QSI);

  bond_v11<<<256, 1024, 0, stream>>>(edge_feat, srcS, dstS, eidS, bondW0eT, bondW1T,
                                     PSI, QSI, bbm1, bbg1, concat);

  agg_kernel<<<(NN + 3) / 4, 256, 0, stream>>>(offsets, concat, agg);

  zn_kernel<<<196, 512, 0, stream>>>(node_inp, coords, gstate, znW, nbm0, nbg0, ZN);

  node_v11<<<196, 1024, 0, stream>>>(agg, ZN, nodeWaggT, nodeW1T,
                                     nbm1, nbg1, gamma, beta, (float*)d_out);
}

// Round 13
// 521.281 us; speedup vs baseline: 1.7771x; 1.7771x over previous
//
#include <hip/hip_runtime.h>
#include <stdint.h>

// GeneralConv fused pipeline for MI355X (gfx950) — v13.
// = v10 exactly (proven best: 648us total; bond 378us, VGPR 124, no spill)
// + ONE conservative change: sigmoid's divide -> __builtin_amdgcn_rcpf
// (single v_rcp_f32 instead of IEEE divide's rcp+Newton sequence).
// v12's inline-asm v_cvt_pk_bf16_f32 produced NaN (guide T12 warned: don't
// hand-write cvt_pk) — reverted to the proven manual RNE pack.

#define NN 50000
#define NE 800000
#define NPART 196        // ceil(NN/256)
#define NTILE_N 1563     // ceil(NN/32)
#define NTILE_E16 50000  // NE/16

typedef short bf16x8 __attribute__((ext_vector_type(8)));
typedef float f32x4 __attribute__((ext_vector_type(4)));

#define MFMA16(a, b, c) __builtin_amdgcn_mfma_f32_16x16x32_bf16((a), (b), (c), 0, 0, 0)

union U8 { uint4 q; bf16x8 v; };

__device__ __forceinline__ uint32_t f2bf(float f) {
  union { float f; uint32_t u; } x; x.f = f;
  uint32_t u = x.u;
  u += 0x7FFFu + ((u >> 16) & 1u);   // RNE
  return u >> 16;
}
__device__ __forceinline__ float bf2f(uint32_t lo16) {
  union { uint32_t u; float f; } x; x.u = lo16 << 16; return x.f;
}
__device__ __forceinline__ float sigm(float x) {
  // 1/(1+e^-x): e^-x >= 0 so the rcp argument is >= 1 (safe, ~1ulp).
  return __builtin_amdgcn_rcpf(1.0f + __expf(-x));
}
__device__ __forceinline__ float silu(float x) { return x * sigm(x); }
__device__ __forceinline__ uint32_t packbf2(float a, float b) {
  return f2bf(a) | (f2bf(b) << 16);
}
__device__ __forceinline__ bf16x8 pack8(float4 a, float4 b) {
  U8 u;
  u.q.x = packbf2(a.x, a.y); u.q.y = packbf2(a.z, a.w);
  u.q.z = packbf2(b.x, b.y); u.q.w = packbf2(b.z, b.w);
  return u.v;
}
__device__ __forceinline__ f32x4 cvt4u(uint32_t a, uint32_t b) {
  f32x4 r;
  r[0] = bf2f(a & 0xffffu); r[1] = bf2f(a >> 16);
  r[2] = bf2f(b & 0xffffu); r[3] = bf2f(b >> 16);
  return r;
}
__device__ __forceinline__ f32x4 add4(f32x4 a, f32x4 b) {
  f32x4 r; r[0] = a[0] + b[0]; r[1] = a[1] + b[1]; r[2] = a[2] + b[2]; r[3] = a[3] + b[3];
  return r;
}
// swizzled LDS weight-fragment read: region layout [rows][128 k] bf16, 256B rows
__device__ __forceinline__ bf16x8 ldw(const char* base, int row, int kc, int lg) {
  return *(const bf16x8*)(base + ((row * 256 + kc * 64 + lg * 16) ^ ((row & 7) << 4)));
}
__device__ __forceinline__ void stage_w(char* dst, const unsigned short* src,
                                        int tid, int nthr) {
  for (int g = tid; g < 4096; g += nthr) {
    int row = g >> 4, slot = g & 15;
    *(uint4*)(dst + ((row * 256 + slot * 16) ^ ((row & 7) << 4))) =
        *(const uint4*)(src + row * 128 + slot * 8);
  }
}

// ---------------------------------------------------------------------------
// combined weight pack: 12 transpose jobs + zn pack, one launch
// ---------------------------------------------------------------------------
__global__ __launch_bounds__(256) void packmulti(
    const float* __restrict__ bWm0, const float* __restrict__ bWg0,
    const float* __restrict__ bWm1, const float* __restrict__ bWg1,
    const float* __restrict__ nWm0, const float* __restrict__ nWg0,
    const float* __restrict__ nWm1, const float* __restrict__ nWg1,
    unsigned short* __restrict__ bondW0eT, unsigned short* __restrict__ bondW1T,
    unsigned short* __restrict__ pqPW, unsigned short* __restrict__ pqQW,
    unsigned short* __restrict__ nodeWaggT, unsigned short* __restrict__ nodeW1T,
    unsigned short* __restrict__ znW) {
  int b = blockIdx.x;
  if (b < 768) {
    int job = b >> 6;
    const float* W; int rb; unsigned short* WT; int c0;
    switch (job) {
      case 0:  W = bWm0; rb = 256; WT = bondW0eT;  c0 = 0;   break;
      case 1:  W = bWg0; rb = 256; WT = bondW0eT;  c0 = 128; break;
      case 2:  W = bWm1; rb = 0;   WT = bondW1T;   c0 = 0;   break;
      case 3:  W = bWg1; rb = 0;   WT = bondW1T;   c0 = 128; break;
      case 4:  W = bWm0; rb = 0;   WT = pqPW;      c0 = 0;   break;
      case 5:  W = bWg0; rb = 0;   WT = pqPW;      c0 = 128; break;
      case 6:  W = bWm0; rb = 128; WT = pqQW;      c0 = 0;   break;
      case 7:  W = bWg0; rb = 128; WT = pqQW;      c0 = 128; break;
      case 8:  W = nWm0; rb = 128; WT = nodeWaggT; c0 = 0;   break;
      case 9:  W = nWg0; rb = 128; WT = nodeWaggT; c0 = 128; break;
      case 10: W = nWm1; rb = 0;   WT = nodeW1T;   c0 = 0;   break;
      default: W = nWg1; rb = 0;   WT = nodeW1T;   c0 = 128; break;
    }
    int id = (b & 63) * 256 + threadIdx.x;
    int c = id >> 7, k = id & 127;
    WT[(size_t)(c0 + c) * 128 + k] = (unsigned short)f2bf(W[(size_t)(rb + k) * 128 + c]);
  } else {
    // znW [256 c][288 k]: k<128 node_inp rows, 128..255 coords rows(+256), 256 = gs row 384
    int id = (b - 768) * 256 + threadIdx.x;
    if (id >= 256 * 288) return;
    int c = id / 288, k = id - c * 288;
    const float* W = (c < 128) ? nWm0 : nWg0;
    int cc = c & 127;
    float v = 0.0f;
    if (k < 128) v = W[(size_t)k * 128 + cc];
    else if (k < 256) v = W[(size_t)(128 + k) * 128 + cc];   // row 256+(k-128)
    else if (k == 256) v = W[(size_t)384 * 128 + cc];
    znW[id] = (unsigned short)f2bf(v);
  }
}

// ---------------- CSR build ----------------
__global__ __launch_bounds__(256) void hist_kernel(const int* __restrict__ ei,
                                                   int* __restrict__ cnt) {
  int e = blockIdx.x * 256 + threadIdx.x;
  if (e < NE) atomicAdd(&cnt[ei[e]], 1);
}

__global__ __launch_bounds__(256) void scan1(const int* __restrict__ cnt,
                                             int* __restrict__ partials) {
  int t = threadIdx.x;
  int i = blockIdx.x * 256 + t;
  int v = (i < NN) ? cnt[i] : 0;
#pragma unroll
  for (int d = 1; d < 64; d <<= 1) v += __shfl_xor(v, d, 64);
  __shared__ int ws4[4];
  if ((t & 63) == 0) ws4[t >> 6] = v;
  __syncthreads();
  if (t == 0) partials[blockIdx.x] = ws4[0] + ws4[1] + ws4[2] + ws4[3];
}

__global__ __launch_bounds__(256) void scan2(int* __restrict__ partials,
                                             int* __restrict__ offsets) {
  int t = threadIdx.x;
  int v = (t < NPART) ? partials[t] : 0;
  int incl = v;
#pragma unroll
  for (int d = 1; d < 64; d <<= 1) {
    int u = __shfl_up(incl, d, 64);
    if ((t & 63) >= d) incl += u;
  }
  __shared__ int wsum[4];
  if ((t & 63) == 63) wsum[t >> 6] = incl;
  __syncthreads();
  int add = 0;
  for (int w = 0; w < (t >> 6); ++w) add += wsum[w];
  incl += add;
  if (t < NPART) partials[t] = incl - v;
  if (t == 255) offsets[NN] = incl;
}

__global__ __launch_bounds__(256) void scan3(const int* __restrict__ cnt,
                                             const int* __restrict__ partials,
                                             int* __restrict__ offsets,
                                             int* __restrict__ cursor) {
  int t = threadIdx.x;
  int i = blockIdx.x * 256 + t;
  int v = (i < NN) ? cnt[i] : 0;
  int incl = v;
#pragma unroll
  for (int d = 1; d < 64; d <<= 1) {
    int u = __shfl_up(incl, d, 64);
    if ((t & 63) >= d) incl += u;
  }
  __shared__ int wsum[4];
  if ((t & 63) == 63) wsum[t >> 6] = incl;
  __syncthreads();
  int add = partials[blockIdx.x];
  for (int w = 0; w < (t >> 6); ++w) add += wsum[w];
  int excl = incl - v + add;
  if (i < NN) { offsets[i] = excl; cursor[i] = excl; }
}

__global__ __launch_bounds__(256) void fill_kernel(const int* __restrict__ ei,
                                                   int* __restrict__ cursor,
                                                   int* __restrict__ eidS,
                                                   int* __restrict__ srcS,
                                                   int* __restrict__ dstS) {
  int e = blockIdx.x * 256 + threadIdx.x;
  if (e >= NE) return;
  int s = ei[e], d = ei[NE + e];
  int pos = atomicAdd(&cursor[s], 1);
  eidS[pos] = e; srcS[pos] = s; dstS[pos] = d;
}

// ---------------------------------------------------------------------------
// pq_kernel: INTERLEAVED tables.
// PSI[n][hf][lg][m4|g4]: m = (ni@Wm0[0:128]+bm0)[hf*16+lg*4..+3], g analog.
// QSI same from Wm0[128:256]/Wg0[128:256], no bias.
// ---------------------------------------------------------------------------
template <bool BIAS>
__device__ __forceinline__ void pq_table(const char* wbase, const bf16x8 (&xf)[2][4],
                                         const float* bm, const float* bg,
                                         unsigned short* out, int tb, int lg, int lr) {
  f32x4 acc[2][16] = {};
#pragma unroll
  for (int kc = 0; kc < 4; ++kc)
#pragma unroll
    for (int cf = 0; cf < 16; ++cf) {
      bf16x8 a = ldw(wbase, cf * 16 + lr, kc, lg);
      acc[0][cf] = MFMA16(a, xf[0][kc], acc[0][cf]);
      acc[1][cf] = MFMA16(a, xf[1][kc], acc[1][cf]);
    }
#pragma unroll
  for (int cf = 0; cf < 16; ++cf) {
    int c = cf * 16 + lg * 4;                 // channel within branch block
    float4 b = make_float4(0.f, 0.f, 0.f, 0.f);
    if (BIAS) b = *(const float4*)((cf < 8) ? (bm + c) : (bg + (c - 128)));
    int hf = cf & 7;
    int off = hf * 32 + lg * 8 + ((cf >= 8) ? 4 : 0);   // interleaved position
#pragma unroll
    for (int et = 0; et < 2; ++et) {
      int n = tb + et * 16 + lr;
      if (n < NN) {
        f32x4 v = acc[et][cf];
        uint2 pk = make_uint2(packbf2(v[0] + b.x, v[1] + b.y),
                              packbf2(v[2] + b.z, v[3] + b.w));
        *(uint2*)(out + (size_t)n * 256 + off) = pk;
      }
    }
  }
}

__global__ __launch_bounds__(512, 2) void pq_kernel(
    const float* __restrict__ ni,
    const unsigned short* __restrict__ pW, const unsigned short* __restrict__ qW,
    const float* __restrict__ bbm0, const float* __restrict__ bbg0,
    unsigned short* __restrict__ PSI, unsigned short* __restrict__ QSI) {
  __shared__ char sm[131072];
  const int t = threadIdx.x, lane = t & 63, wv = t >> 6, lg = lane >> 4, lr = lane & 15;
  stage_w(sm, pW, t, 512);
  stage_w(sm + 65536, qW, t, 512);
  __syncthreads();
  int tile = blockIdx.x * 8 + wv;
  if (tile >= NTILE_N) return;
  int tb = tile * 32;
  int n0 = min(tb + lr, NN - 1), n1 = min(tb + 16 + lr, NN - 1);
  bf16x8 xf[2][4];
#pragma unroll
  for (int kc = 0; kc < 4; ++kc) {
    const float* p0 = ni + (size_t)n0 * 128 + kc * 32 + lg * 8;
    const float* p1 = ni + (size_t)n1 * 128 + kc * 32 + lg * 8;
    xf[0][kc] = pack8(((const float4*)p0)[0], ((const float4*)p0)[1]);
    xf[1][kc] = pack8(((const float4*)p1)[0], ((const float4*)p1)[1]);
  }
  pq_table<true>(sm, xf, bbm0, bbg0, PSI, tb, lg, lr);
  pq_table<false>(sm + 65536, xf, nullptr, nullptr, QSI, tb, lg, lr);
}

// ---------------------------------------------------------------------------
// zn_kernel: Znode[n][256] bf16 = [zm|zg] (plain layout), z = ni@W[0:128] +
// coords@W[256:384] + gs*W[384] + b0. Weights [256][288] = 144KB LDS.
// ---------------------------------------------------------------------------
__global__ __launch_bounds__(512, 2) void zn_kernel(
    const float* __restrict__ ni, const float* __restrict__ coords,
    const float* __restrict__ gs, const unsigned short* __restrict__ znW,
    const float* __restrict__ nbm0, const float* __restrict__ nbg0,
    unsigned short* __restrict__ ZN) {
  __shared__ char sm[147456];
  const int t = threadIdx.x, lane = t & 63, wv = t >> 6, lg = lane >> 4, lr = lane & 15;
  for (int g = t; g < 256 * 36; g += 512) {
    int row = g / 36, slot = g - row * 36;
    *(uint4*)(sm + ((row * 576 + slot * 16) ^ ((row & 7) << 4))) =
        *(const uint4*)(znW + row * 288 + slot * 8);
  }
  __syncthreads();
  int tile = blockIdx.x * 8 + wv;
  if (tile >= NTILE_N) return;
  int tb = tile * 32;
  int n0 = min(tb + lr, NN - 1), n1 = min(tb + 16 + lr, NN - 1);
  f32x4 acc[2][16] = {};
#pragma unroll
  for (int kc = 0; kc < 9; ++kc) {
    bf16x8 x0, x1;
    if (kc < 8) {
      const float* base = (kc < 4) ? ni : coords;
      int ko = (kc & 3) * 32 + lg * 8;
      const float* p0 = base + (size_t)n0 * 128 + ko;
      const float* p1 = base + (size_t)n1 * 128 + ko;
      x0 = pack8(((const float4*)p0)[0], ((const float4*)p0)[1]);
      x1 = pack8(((const float4*)p1)[0], ((const float4*)p1)[1]);
    } else {
      U8 z0, z1;
      z0.q = make_uint4(0, 0, 0, 0); z1.q = make_uint4(0, 0, 0, 0);
      if (lg == 0) { z0.q.x = f2bf(gs[n0]); z1.q.x = f2bf(gs[n1]); }
      x0 = z0.v; x1 = z1.v;
    }
#pragma unroll
    for (int cf = 0; cf < 16; ++cf) {
      int row = cf * 16 + lr;
      bf16x8 a = *(const bf16x8*)(sm + ((row * 576 + kc * 64 + lg * 16) ^ ((row & 7) << 4)));
      acc[0][cf] = MFMA16(a, x0, acc[0][cf]);
      acc[1][cf] = MFMA16(a, x1, acc[1][cf]);
    }
  }
#pragma unroll
  for (int cf = 0; cf < 16; ++cf) {
    int c = cf * 16 + lg * 4;
    float4 b = *(const float4*)((cf < 8) ? (nbm0 + c) : (nbg0 + (c - 128)));
#pragma unroll
    for (int et = 0; et < 2; ++et) {
      int n = tb + et * 16 + lr;
      if (n < NN) {
        f32x4 v = acc[et][cf];
        uint2 pk = make_uint2(packbf2(v[0] + b.x, v[1] + b.y),
                              packbf2(v[2] + b.z, v[3] + b.w));
        *(uint2*)(ZN + (size_t)n * 256 + c) = pk;
      }
    }
  }
}

// ---------------------------------------------------------------------------
// layer2 (32-row, node): silu(acc) -> per-wave LDS scratch [32][72B] -> B-frags
// -> MFMA with LDS-staged W1 rows [rowoff..rowoff+128).
// ---------------------------------------------------------------------------
__device__ __forceinline__ void layer2(const f32x4 (&acc)[2][8], f32x4 (&acc2)[2][8],
                                       const char* w1, int rowoff, char* scr,
                                       int lg, int lr) {
#pragma unroll
  for (int q = 0; q < 4; ++q) {
#pragma unroll
    for (int hq = 0; hq < 2; ++hq) {
      int hf = q * 2 + hq;
#pragma unroll
      for (int et = 0; et < 2; ++et) {
        f32x4 z = acc[et][hf];
        uint2 pk = make_uint2(packbf2(silu(z[0]), silu(z[1])),
                              packbf2(silu(z[2]), silu(z[3])));
        *(uint2*)(scr + (et * 16 + lr) * 72 + hq * 32 + lg * 8) = pk;
      }
    }
#pragma unroll
    for (int et = 0; et < 2; ++et) {
      bf16x8 h = *(const bf16x8*)(scr + (et * 16 + lr) * 72 + lg * 16);
#pragma unroll
      for (int hf2 = 0; hf2 < 8; ++hf2) {
        bf16x8 a = ldw(w1, rowoff + hf2 * 16 + lr, q, lg);
        acc2[et][hf2] = MFMA16(a, h, acc2[et][hf2]);
      }
    }
  }
}

// 16-row variant for bond
__device__ __forceinline__ void layer2_16(const f32x4 (&acc)[8], f32x4 (&acc2)[8],
                                          const char* w1, int rowoff, char* scr,
                                          int lg, int lr) {
#pragma unroll
  for (int q = 0; q < 4; ++q) {
#pragma unroll
    for (int hq = 0; hq < 2; ++hq) {
      f32x4 z = acc[q * 2 + hq];
      uint2 pk = make_uint2(packbf2(silu(z[0]), silu(z[1])),
                            packbf2(silu(z[2]), silu(z[3])));
      *(uint2*)(scr + lr * 72 + hq * 32 + lg * 8) = pk;
    }
    bf16x8 h = *(const bf16x8*)(scr + lr * 72 + lg * 16);
#pragma unroll
    for (int hf2 = 0; hf2 < 8; ++hf2) {
      bf16x8 a = ldw(w1, rowoff + hf2 * 16 + lr, q, lg);
      acc2[hf2] = MFMA16(a, h, acc2[hf2]);
    }
  }
}

// ---------------------------------------------------------------------------
// bond_v13: v10 body — 16-edge tiles, CSR order, ALL gathers staged up front,
// next-tile index prefetch, barrier-free tile loop.
// ---------------------------------------------------------------------------
__global__ __launch_bounds__(512, 2) void bond_v13(
    const float* __restrict__ ef,
    const int* __restrict__ srcS, const int* __restrict__ dstS,
    const int* __restrict__ eidS,
    const unsigned short* __restrict__ W0eT, const unsigned short* __restrict__ W1T,
    const unsigned short* __restrict__ PSI, const unsigned short* __restrict__ QSI,
    const float* __restrict__ bbm1, const float* __restrict__ bbg1,
    unsigned short* __restrict__ concat) {
  __shared__ char sm[141312];   // W0e 64K | W1 64K | biases 1K | scratch 8*1152
  const int t = threadIdx.x, lane = t & 63, wv = t >> 6, lg = lane >> 4, lr = lane & 15;
  stage_w(sm, W0eT, t, 512);          // rows 0..127 m, 128..255 g (K=128)
  stage_w(sm + 65536, W1T, t, 512);   // rows 0..127 W1m, 128..255 W1g
  if (t < 128) {
    ((float*)(sm + 131072))[t] = bbm1[t];
    ((float*)(sm + 131584))[t] = bbg1[t];
  }
  __syncthreads();
  char* scr = sm + 132096 + wv * 1152;

  const int wid = blockIdx.x * 8 + wv;   // 2048 waves, ~25 tiles each
  const int start = wid * 25;
  const int end = min(start + 25, NTILE_E16);
  if (start >= end) return;

  // preload first tile's indices (per-lane: edge tb+lr)
  int s0 = srcS[start * 16 + lr];
  int d0 = dstS[start * 16 + lr];
  int ed0 = eidS[start * 16 + lr];

  for (int tile = start; tile < end; ++tile) {
    const int tb = tile * 16;
    // ---- issue ALL gathers for this tile as one batch ----
    uint4 P[8], Q[8];
    const unsigned short* pp = PSI + (size_t)s0 * 256 + lg * 8;
    const unsigned short* qq = QSI + (size_t)d0 * 256 + lg * 8;
#pragma unroll
    for (int hf = 0; hf < 8; ++hf) {
      P[hf] = *(const uint4*)(pp + hf * 32);
      Q[hf] = *(const uint4*)(qq + hf * 32);
    }
    float4 E[8];
    const float* eb = ef + (size_t)ed0 * 128 + lg * 8;
#pragma unroll
    for (int kq = 0; kq < 8; ++kq)
      E[kq] = ((const float4*)(eb + (kq >> 1) * 32))[kq & 1];
    // ---- prefetch next tile's indices (independent of this tile) ----
    if (tile + 1 < end) {
      int en = (tile + 1) * 16 + lr;
      s0 = srcS[en]; d0 = dstS[en]; ed0 = eidS[en];
    }

    // ---- acc init from P+Q (interleaved m4|g4) ----
    f32x4 accm[8], accg[8];
#pragma unroll
    for (int hf = 0; hf < 8; ++hf) {
      accm[hf] = add4(cvt4u(P[hf].x, P[hf].y), cvt4u(Q[hf].x, Q[hf].y));
      accg[hf] = add4(cvt4u(P[hf].z, P[hf].w), cvt4u(Q[hf].z, Q[hf].w));
    }

    // ---- layer1: + edge_feat @ W0e ----
#pragma unroll
    for (int kc = 0; kc < 4; ++kc) {
      bf16x8 x = pack8(E[kc * 2], E[kc * 2 + 1]);
#pragma unroll
      for (int hf = 0; hf < 8; ++hf) {
        accm[hf] = MFMA16(ldw(sm, hf * 16 + lr, kc, lg), x, accm[hf]);
        accg[hf] = MFMA16(ldw(sm, 128 + hf * 16 + lr, kc, lg), x, accg[hf]);
      }
    }

    // ---- layer2 both branches ----
    f32x4 acc2m[8] = {};
    layer2_16(accm, acc2m, sm + 65536, 0, scr, lg, lr);
    f32x4 acc2g[8] = {};
    layer2_16(accg, acc2g, sm + 65536, 128, scr, lg, lr);

    // ---- combine m * sigmoid(g); contiguous store at CSR slot ----
#pragma unroll
    for (int hf2 = 0; hf2 < 8; ++hf2) {
      float4 b1m = *(const float4*)(sm + 131072 + (hf2 * 16 + lg * 4) * 4);
      float4 b1g = *(const float4*)(sm + 131584 + (hf2 * 16 + lg * 4) * 4);
      f32x4 m = acc2m[hf2], g = acc2g[hf2];
      uint2 pk = make_uint2(
          packbf2((m[0] + b1m.x) * sigm(g[0] + b1g.x),
                  (m[1] + b1m.y) * sigm(g[1] + b1g.y)),
          packbf2((m[2] + b1m.z) * sigm(g[2] + b1g.z),
                  (m[3] + b1m.w) * sigm(g[3] + b1g.w)));
      *(uint2*)(concat + (size_t)(tb + lr) * 128 + hf2 * 16 + lg * 4) = pk;
    }
  }
}

// segment mean over CSR-contiguous concat rows -> agg[N][128] bf16 (streaming)
__global__ __launch_bounds__(256) void agg_kernel(const int* __restrict__ offsets,
                                                  const unsigned short* __restrict__ concat,
                                                  unsigned short* __restrict__ agg) {
  int n = blockIdx.x * 4 + (threadIdx.x >> 6);
  if (n >= NN) return;
  int lane = threadIdx.x & 63;
  int s0 = offsets[n], s1 = offsets[n + 1];
  float a0 = 0.f, a1 = 0.f;
  const uint32_t* p = (const uint32_t*)concat + lane;
  for (int s = s0; s < s1; ++s) {
    uint32_t v = p[(size_t)s * 64];
    a0 += bf2f(v & 0xffffu);
    a1 += bf2f(v >> 16);
  }
  float inv = (s1 > s0) ? 1.f / (float)(s1 - s0) : 0.f;
  ((uint32_t*)agg)[(size_t)n * 64 + lane] = packbf2(a0 * inv, a1 * inv);
}

// ---------------------------------------------------------------------------
// node_v13: acc init from Znode (plain layout), + agg@Wagg (K=128), layer2,
// fused LayerNorm.
// ---------------------------------------------------------------------------
__global__ __launch_bounds__(512, 2) void node_v13(
    const unsigned short* __restrict__ agg, const unsigned short* __restrict__ ZN,
    const unsigned short* __restrict__ WaggT, const unsigned short* __restrict__ W1T,
    const float* __restrict__ nbm1, const float* __restrict__ nbg1,
    const float* __restrict__ gamma, const float* __restrict__ beta,
    float* __restrict__ out) {
  __shared__ char sm[151552];   // Wagg 64K | W1 64K | consts 2K | scratch 8*2304
  const int t = threadIdx.x, lane = t & 63, wv = t >> 6, lg = lane >> 4, lr = lane & 15;
  stage_w(sm, WaggT, t, 512);
  stage_w(sm + 65536, W1T, t, 512);
  if (t < 128) {
    ((float*)(sm + 131072))[t] = nbm1[t];
    ((float*)(sm + 131584))[t] = nbg1[t];
    ((float*)(sm + 132096))[t] = gamma[t];
    ((float*)(sm + 132608))[t] = beta[t];
  }
  __syncthreads();
  char* scr = sm + 133120 + wv * 2304;

  int tile = blockIdx.x * 8 + wv;
  if (tile >= NTILE_N) return;
  int tb = tile * 32;
  int n0 = min(tb + lr, NN - 1), n1 = min(tb + 16 + lr, NN - 1);

  f32x4 accm[2][8], accg[2][8];
  {
    uint2 zm0[8], zg0[8], zm1[8], zg1[8];
#pragma unroll
    for (int hf = 0; hf < 8; ++hf) {
      const unsigned short* p0 = ZN + (size_t)n0 * 256 + hf * 16 + lg * 4;
      const unsigned short* p1 = ZN + (size_t)n1 * 256 + hf * 16 + lg * 4;
      zm0[hf] = *(const uint2*)p0; zg0[hf] = *(const uint2*)(p0 + 128);
      zm1[hf] = *(const uint2*)p1; zg1[hf] = *(const uint2*)(p1 + 128);
    }
#pragma unroll
    for (int hf = 0; hf < 8; ++hf) {
      accm[0][hf] = cvt4u(zm0[hf].x, zm0[hf].y); accg[0][hf] = cvt4u(zg0[hf].x, zg0[hf].y);
      accm[1][hf] = cvt4u(zm1[hf].x, zm1[hf].y); accg[1][hf] = cvt4u(zg1[hf].x, zg1[hf].y);
    }
  }
#pragma unroll
  for (int kc = 0; kc < 4; ++kc) {
    bf16x8 x0 = *(const bf16x8*)(agg + (size_t)n0 * 128 + kc * 32 + lg * 8);
    bf16x8 x1 = *(const bf16x8*)(agg + (size_t)n1 * 128 + kc * 32 + lg * 8);
#pragma unroll
    for (int hf = 0; hf < 8; ++hf) {
      bf16x8 am = ldw(sm, hf * 16 + lr, kc, lg);
      bf16x8 ag = ldw(sm, 128 + hf * 16 + lr, kc, lg);
      accm[0][hf] = MFMA16(am, x0, accm[0][hf]);
      accm[1][hf] = MFMA16(am, x1, accm[1][hf]);
      accg[0][hf] = MFMA16(ag, x0, accg[0][hf]);
      accg[1][hf] = MFMA16(ag, x1, accg[1][hf]);
    }
  }

  f32x4 acc2m[2][8] = {};
  layer2(accm, acc2m, sm + 65536, 0, scr, lg, lr);
  f32x4 acc2g[2][8] = {};
  layer2(accg, acc2g, sm + 65536, 128, scr, lg, lr);

#pragma unroll
  for (int et = 0; et < 2; ++et) {
    float v[8][4];
    float s = 0.f, ss = 0.f;
#pragma unroll
    for (int hf2 = 0; hf2 < 8; ++hf2) {
      float4 b1m = *(const float4*)(sm + 131072 + (hf2 * 16 + lg * 4) * 4);
      float4 b1g = *(const float4*)(sm + 131584 + (hf2 * 16 + lg * 4) * 4);
      f32x4 m = acc2m[et][hf2], g = acc2g[et][hf2];
      v[hf2][0] = (m[0] + b1m.x) * sigm(g[0] + b1g.x);
      v[hf2][1] = (m[1] + b1m.y) * sigm(g[1] + b1g.y);
      v[hf2][2] = (m[2] + b1m.z) * sigm(g[2] + b1g.z);
      v[hf2][3] = (m[3] + b1m.w) * sigm(g[3] + b1g.w);
#pragma unroll
      for (int r = 0; r < 4; ++r) { s += v[hf2][r]; ss += v[hf2][r] * v[hf2][r]; }
    }
    s += __shfl_xor(s, 16, 64);  ss += __shfl_xor(ss, 16, 64);
    s += __shfl_xor(s, 32, 64);  ss += __shfl_xor(ss, 32, 64);
    float mu = s * 0.0078125f;
    float var = ss * 0.0078125f - mu * mu;
    float rs = rsqrtf(var + 1e-5f);
    int n = tb + et * 16 + lr;
    if (n < NN) {
#pragma unroll
      for (int hf2 = 0; hf2 < 8; ++hf2) {
        float4 gm = *(const float4*)(sm + 132096 + (hf2 * 16 + lg * 4) * 4);
        float4 bt = *(const float4*)(sm + 132608 + (hf2 * 16 + lg * 4) * 4);
        float4 o;
        o.x = (v[hf2][0] - mu) * rs * gm.x + bt.x;
        o.y = (v[hf2][1] - mu) * rs * gm.y + bt.y;
        o.z = (v[hf2][2] - mu) * rs * gm.z + bt.z;
        o.w = (v[hf2][3] - mu) * rs * gm.w + bt.w;
        *(float4*)(out + (size_t)n * 128 + hf2 * 16 + lg * 4) = o;
      }
    }
  }
}

extern "C" void kernel_launch(void* const* d_in, const int* in_sizes, int n_in,
                              void* d_out, int out_size, void* d_ws, size_t ws_size,
                              hipStream_t stream) {
  const float* node_inp = (const float*)d_in[0];
  const float* edge_feat = (const float*)d_in[1];
  const float* gstate = (const float*)d_in[2];
  const float* coords = (const float*)d_in[4];
  const int* edge_index = (const int*)d_in[5];
  const float* bWm0 = (const float*)d_in[6];  const float* bbm0 = (const float*)d_in[7];
  const float* bWm1 = (const float*)d_in[8];  const float* bbm1 = (const float*)d_in[9];
  const float* bWg0 = (const float*)d_in[10]; const float* bbg0 = (const float*)d_in[11];
  const float* bWg1 = (const float*)d_in[12]; const float* bbg1 = (const float*)d_in[13];
  const float* nWm0 = (const float*)d_in[14]; const float* nbm0 = (const float*)d_in[15];
  const float* nWm1 = (const float*)d_in[16]; const float* nbm1 = (const float*)d_in[17];
  const float* nWg0 = (const float*)d_in[18]; const float* nbg0 = (const float*)d_in[19];
  const float* nWg1 = (const float*)d_in[20]; const float* nbg1 = (const float*)d_in[21];
  const float* gamma = (const float*)d_in[22]; const float* beta = (const float*)d_in[23];

  char* ws = (char*)d_ws;
  size_t o = 0;
  auto alloc = [&](size_t bytes) {
    size_t r = o; o = (o + bytes + 255) & ~(size_t)255; return r;
  };
  unsigned short* QSI  = (unsigned short*)(ws + alloc((size_t)NN * 256 * 2)); // 25.6MB
  int* offsets         = (int*)(ws + alloc((size_t)(NN + 1) * 4));
  int* eidS            = (int*)(ws + alloc((size_t)NE * 4));
  int* srcS            = (int*)(ws + alloc((size_t)NE * 4));
  int* dstS            = (int*)(ws + alloc((size_t)NE * 4));
  unsigned short* bondW0eT  = (unsigned short*)(ws + alloc(256 * 128 * 2));
  unsigned short* bondW1T   = (unsigned short*)(ws + alloc(256 * 128 * 2));
  unsigned short* pqPW      = (unsigned short*)(ws + alloc(256 * 128 * 2));
  unsigned short* pqQW      = (unsigned short*)(ws + alloc(256 * 128 * 2));
  unsigned short* znW       = (unsigned short*)(ws + alloc(256 * 288 * 2));
  unsigned short* nodeWaggT = (unsigned short*)(ws + alloc(256 * 128 * 2));
  unsigned short* nodeW1T   = (unsigned short*)(ws + alloc(256 * 128 * 2));
  char* concatR        = ws + alloc((size_t)NE * 128 * 2);                   // 204.8MB
  // overlays (lifetime-disjoint):
  unsigned short* PSI = (unsigned short*)d_out;          // dead before node_v13 writes
  unsigned short* agg = QSI;                             // QSI dead after bond
  int* cnt      = (int*)concatR;                         // pre-bond
  int* partials = (int*)(concatR + (1 << 20));           // pre-bond
  int* cursor   = (int*)(concatR + (2 << 20));           // pre-bond
  unsigned short* ZN = (unsigned short*)(concatR + (4 << 20));  // after agg
  unsigned short* concat = (unsigned short*)concatR;

  hipMemsetAsync(cnt, 0, (size_t)NN * 4, stream);

  packmulti<<<1056, 256, 0, stream>>>(bWm0, bWg0, bWm1, bWg1, nWm0, nWg0, nWm1, nWg1,
                                      bondW0eT, bondW1T, pqPW, pqQW,
                                      nodeWaggT, nodeW1T, znW);

  hist_kernel<<<NE / 256, 256, 0, stream>>>(edge_index, cnt);
  scan1<<<NPART, 256, 0, stream>>>(cnt, partials);
  scan2<<<1, 256, 0, stream>>>(partials, offsets);
  scan3<<<NPART, 256, 0, stream>>>(cnt, partials, offsets, cursor);
  fill_kernel<<<NE / 256, 256, 0, stream>>>(edge_index, cursor, eidS, srcS, dstS);

  pq_kernel<<<196, 512, 0, stream>>>(node_inp, pqPW, pqQW, bbm0, bbg0, PSI, QSI);

  bond_v13<<<256, 512, 0, stream>>>(edge_feat, srcS, dstS, eidS, bondW0eT, bondW1T,
                                    PSI, QSI, bbm1, bbg1, concat);

  agg_kernel<<<(NN + 3) / 4, 256, 0, stream>>>(offsets, concat, agg);

  zn_kernel<<<196, 512, 0, stream>>>(node_inp, coords, gstate, znW, nbm0, nbg0, ZN);

  node_v13<<<196, 512, 0, stream>>>(agg, ZN, nodeWaggT, nodeW1T,
                                    nbm1, nbg1, gamma, beta, (float*)d_out);
}